// Round 1
// baseline (1997.442 us; speedup 1.0000x reference)
//
#include <hip/hip_runtime.h>

#define PI_D 3.14159265358979323846

// Problem constants
//  x[l2,part]: (8192, 15, l2+1, 5, 16)   n-stride = 1200*(l2+1)
//  w[l1,part]: (l1+1, 15, 5, 16, 16)     m-stride = 19200, t-stride = 1280, p 256, i 16, j 1
//  b[l,part]:  (1, l+1, 5, 16)           lr-stride = 80
//  out[l,part]:(8192, l+1, 5, 16) concatenated; base = 655360*(l+1)*(l+part)
//
// K layout (4800): l2{ part'{ kx{ t{ i(16) }}}}  -> 300 blocks of 16 (i innermost)
//   per-l2 block counts: 30,60,90,120 ; offsets 0,30,90,180
// col layout (320): l{ part{ lr{ j(16) }}} ; offsets 0,32,96,192
// ws: G[4^7]=16384 floats at offset 0; W[p][4800][320] = 7,680,000 floats after.

struct Ptrs8 { const float* p[8]; };

__device__ __forceinline__ double dfact(int n){ double r=1.0; for(int i=2;i<=n;++i) r*=(double)i; return r; }

__device__ double cg_coef(int j1,int m1,int j2,int m2,int j3,int m3){
  if(m1+m2!=m3) return 0.0;
  if(j3<abs(j1-j2)||j3>j1+j2) return 0.0;
  if(abs(m1)>j1||abs(m2)>j2||abs(m3)>j3) return 0.0;
  double pre = sqrt((2.0*j3+1.0)*dfact(j3+j1-j2)*dfact(j3-j1+j2)*dfact(j1+j2-j3)/dfact(j1+j2+j3+1));
  pre *= sqrt(dfact(j3+m3)*dfact(j3-m3)*dfact(j1-m1)*dfact(j1+m1)*dfact(j2-m2)*dfact(j2+m2));
  int kmin = max(0,max(j2-j3-m1,j1-j3+m2));
  int kmax = min(j1+j2-j3,min(j1-m1,j2+m2));
  double s=0.0;
  for(int k=kmin;k<=kmax;++k){
    double d = dfact(k)*dfact(j1+j2-j3-k)*dfact(j1-m1-k)*dfact(j2+m2-k)*dfact(j3-j2+m1+k)*dfact(j3-j1-m2+k);
    s += ((k&1)?-1.0:1.0)/d;
  }
  return pre*s;
}

__device__ __forceinline__ int gidx(int l,int l2,int combo,int lr,int kx,int l1,int m){
  return ((((((l*4+l2)*4+combo)*4+lr)*4+kx)*4+l1)*4+m);
}

// Compute G[l][l2][combo][lr][kx][l1][m] = coef * (T1 +- T2 +- T3)[lr,m,kx]
// combo signs:   T1        T2        T3
//  0 (xr*wr->or): +         +         +
//  1 (xi*wi->or): -         +         -       (= -c*(T1-T2+T3))
//  2 (xr*wi->oi): +         -         -
//  3 (xi*wr->oi): +         +         -
__global__ void g_kernel(float* __restrict__ G){
  int tid = threadIdx.x;
  for(int e=tid;e<16384;e+=blockDim.x) G[e]=0.0f;
  __syncthreads();
  int trip = tid >> 4;          // one (triple) per 16 threads
  int sub  = tid & 15;
  int lr = sub >> 2, m = sub & 3;
  int idx=0;
  for(int l=0;l<4;l++)for(int l1=0;l1<4;l1++){
    int lo=abs(l-l1), hi=min(3,l+l1);
    for(int l2=lo;l2<=hi;l2++){
      if(idx==trip && lr<=l && m<=l1){
        double c = 8.0*PI_D*PI_D/(2.0*l1+1.0)
                 * sqrt((2.0*l+1.0)*(2.0*l1+1.0)/(4.0*PI_D*(2.0*l2+1.0)))
                 * cg_coef(l,0,l1,0,l2,0);
        // T1 at kx = lr+m
        if(lr+m<=l2){
          float f = (float)(c * cg_coef(l,lr,l1,m,l2,lr+m) * ((m&1)?-1.0:1.0));
          G[gidx(l,l2,0,lr,lr+m,l1,m)] += f;
          G[gidx(l,l2,1,lr,lr+m,l1,m)] -= f;
          G[gidx(l,l2,2,lr,lr+m,l1,m)] += f;
          G[gidx(l,l2,3,lr,lr+m,l1,m)] += f;
        }
        if(m>0 && abs(lr-m)<=l2){
          if(lr-m>=0){ // T2 at kx = lr-m
            float f = (float)(c * cg_coef(l,lr,l1,-m,l2,lr-m) * ((l1&1)?-1.0:1.0));
            G[gidx(l,l2,0,lr,lr-m,l1,m)] += f;
            G[gidx(l,l2,1,lr,lr-m,l1,m)] += f;
            G[gidx(l,l2,2,lr,lr-m,l1,m)] -= f;
            G[gidx(l,l2,3,lr,lr-m,l1,m)] += f;
          } else {     // T3 at kx = m-lr
            float f = (float)(c * (((m-lr)&1)?-1.0:1.0) * (((l1+l2)&1)?-1.0:1.0)
                              * cg_coef(l,lr,l1,-m,l2,lr-m));
            G[gidx(l,l2,0,lr,m-lr,l1,m)] += f;
            G[gidx(l,l2,1,lr,m-lr,l1,m)] -= f;
            G[gidx(l,l2,2,lr,m-lr,l1,m)] -= f;
            G[gidx(l,l2,3,lr,m-lr,l1,m)] -= f;
          }
        }
      }
      idx++;
    }
  }
}

__device__ __forceinline__ void decode_kb(int kb,int& l2,int& partp,int& kx,int& t){
  int kbo;
  if(kb<30){l2=0;kbo=0;} else if(kb<90){l2=1;kbo=30;} else if(kb<180){l2=2;kbo=90;} else {l2=3;kbo=180;}
  int rem = kb-kbo;
  int per = (l2+1)*15;
  partp = rem/per;
  int q = rem%per;
  kx = q/15; t = q%15;
}

__device__ __forceinline__ void decode_col(int col,int& l,int& part,int& lr,int& j){
  int co;
  if(col<32){l=0;co=0;} else if(col<96){l=1;co=32;} else if(col<192){l=2;co=96;} else {l=3;co=192;}
  int cr = col-co; int per=(l+1)*16;
  part = cr/per; int q = cr%per; lr = q>>4; j = q&15;
}

// W[p][K][col] = sum_{l1,m} G[l][l2][combo][lr][kx][l1][m] * w[l1,wpart][m,t,p,i,j]
__global__ void w_kernel(const float* __restrict__ G, Ptrs8 wp, float* __restrict__ W){
  long e = (long)blockIdx.x*256 + threadIdx.x;
  if(e >= 5L*4800*320) return;
  int col = (int)(e%320); long r = e/320; int K = (int)(r%4800); int p = (int)(r/4800);
  int i = K & 15; int kb = K >> 4;
  int l2,partp,kx,t; decode_kb(kb,l2,partp,kx,t);
  int l,part,lr,j; decode_col(col,l,part,lr,j);
  int combo = (part==0) ? (partp==0?0:1) : (partp==0?2:3);
  int wpart = (combo==0||combo==3)?0:1;
  int mstart = wpart?1:0;   // imaginary weight has m=0 row masked to zero
  int woff = t*1280 + p*256 + i*16 + j;
  float acc=0.f;
  for(int l1=0;l1<4;l1++){
    const float* wptr = wp.p[l1*2+wpart];
    int gb = ((((l*4+l2)*4+combo)*4+lr)*4+kx)*16 + l1*4;
    for(int m=mstart;m<=l1;m++){
      float g = G[gb+m];
      if(g!=0.f) acc += g * wptr[m*19200 + woff];
    }
  }
  W[e] = acc;
}

// out[n,col,p] = sum_K X[n,K,p] * W[p][K][col] + bias
// block: 64 n-rows x 64 cols, one p. grid (128, 5, 5).
__global__ __launch_bounds__(256) void gemm_kernel(Ptrs8 xp, const float* __restrict__ W,
                                                   Ptrs8 bp, float* __restrict__ out){
  __shared__ __align__(16) float Xs[16][68];
  __shared__ __align__(16) float Ws[16][68];
  int tid = threadIdx.x;
  int nb = blockIdx.x, cb = blockIdx.y, p = blockIdx.z;
  int tx = tid & 15, ty = tid >> 4;
  float acc[4][4] = {};
  const float* Wp = W + (long)p*4800*320;
  int kk = tid & 15;   // i within K-block
  int nl = tid >> 4;   // row-loader lane
  for(int kb=0;kb<300;++kb){
    int l2,partp,kx,t; decode_kb(kb,l2,partp,kx,t);
    const float* xb = xp.p[l2*2+partp];
    int nstride = 1200*(l2+1);
    int off0 = (t*(l2+1)+kx)*80 + p*16;
    #pragma unroll
    for(int rr=0;rr<4;++rr){
      int n = nb*64 + rr*16 + nl;
      Xs[kk][rr*16+nl] = xb[(long)n*nstride + off0 + kk];
    }
    #pragma unroll
    for(int rr=0;rr<4;++rr){
      int e2 = rr*256 + tid;
      int k2 = e2 >> 6, cc = e2 & 63;
      Ws[k2][cc] = Wp[(long)(kb*16+k2)*320 + cb*64 + cc];
    }
    __syncthreads();
    #pragma unroll
    for(int k2=0;k2<16;++k2){
      float4 a4 = *(const float4*)(&Xs[k2][ty*4]);
      float4 b4 = *(const float4*)(&Ws[k2][tx*4]);
      float av[4] = {a4.x,a4.y,a4.z,a4.w};
      float bv[4] = {b4.x,b4.y,b4.z,b4.w};
      #pragma unroll
      for(int ri=0;ri<4;++ri)
        #pragma unroll
        for(int ci=0;ci<4;++ci)
          acc[ri][ci] = fmaf(av[ri], bv[ci], acc[ri][ci]);
    }
    __syncthreads();
  }
  // epilogue: bias + scattered store
  #pragma unroll
  for(int ci=0;ci<4;++ci){
    int col = cb*64 + tx*4 + ci;
    int l,part,lr,j; decode_col(col,l,part,lr,j);
    float bv = 0.f;
    if(!(part==1 && lr==0)) bv = bp.p[l*2+part][lr*80 + p*16 + j];
    long base = 655360L*(l+1)*(l+part);
    int nst = (l+1)*80;
    int inoff = lr*80 + p*16 + j;
    #pragma unroll
    for(int ri=0;ri<4;++ri){
      int n = nb*64 + ty*4 + ri;
      out[base + (long)n*nst + inoff] = acc[ri][ci] + bv;
    }
  }
}

extern "C" void kernel_launch(void* const* d_in, const int* in_sizes, int n_in,
                              void* d_out, int out_size, void* d_ws, size_t ws_size,
                              hipStream_t stream){
  Ptrs8 xp, wp, bp;
  for(int i=0;i<8;i++){
    xp.p[i] = (const float*)d_in[i];
    wp.p[i] = (const float*)d_in[8+i];
    bp.p[i] = (const float*)d_in[16+i];
  }
  float* G = (float*)d_ws;
  float* W = (float*)d_ws + 16384;
  g_kernel<<<dim3(1), dim3(576), 0, stream>>>(G);
  w_kernel<<<dim3(30000), dim3(256), 0, stream>>>(G, wp, W);
  gemm_kernel<<<dim3(128,5,5), dim3(256), 0, stream>>>(xp, W, bp, (float*)d_out);
}

// Round 2
// 495.133 us; speedup vs baseline: 4.0341x; 4.0341x over previous
//
#include <hip/hip_runtime.h>

#define PI_D 3.14159265358979323846

// Layouts
//  x[l2,part]: (8192, 15, l2+1, 5, 16) fp32  n-stride = 1200*(l2+1)
//  w[l1,part]: (l1+1, 15, 5, 16, 16)  fp32   m 19200, t 1280, p 256, i 16, j 1
//  b[l,part]:  (1, l+1, 5, 16)        fp32   lr 80, p 16
//  out[l,part]:(8192, l+1, 5, 16) concat; base = 655360*(l+1)*(l+part)
//
// K (4800): l2{part'{kx{t{i(16)}}}} -> 300 blocks of 16; block offsets 0,30,90,180
// col (320): l{part{lr{j(16)}}};   offsets 0,32,96,192
// ws: G[16384] f32, then W'[p][col 320][K 4800] bf16 (15.36 MB)

typedef __attribute__((ext_vector_type(8))) short short8;
typedef __attribute__((ext_vector_type(4))) float f32x4;

struct Ptrs8 { const float* p[8]; };

__device__ __forceinline__ ushort f2bf(float x){
  uint u = __float_as_uint(x);
  return (ushort)((u + 0x7fffu + ((u>>16)&1u)) >> 16);
}

__device__ __forceinline__ double dfact(int n){ double r=1.0; for(int i=2;i<=n;++i) r*=(double)i; return r; }

__device__ double cg_coef(int j1,int m1,int j2,int m2,int j3,int m3){
  if(m1+m2!=m3) return 0.0;
  if(j3<abs(j1-j2)||j3>j1+j2) return 0.0;
  if(abs(m1)>j1||abs(m2)>j2||abs(m3)>j3) return 0.0;
  double pre = sqrt((2.0*j3+1.0)*dfact(j3+j1-j2)*dfact(j3-j1+j2)*dfact(j1+j2-j3)/dfact(j1+j2+j3+1));
  pre *= sqrt(dfact(j3+m3)*dfact(j3-m3)*dfact(j1-m1)*dfact(j1+m1)*dfact(j2-m2)*dfact(j2+m2));
  int kmin = max(0,max(j2-j3-m1,j1-j3+m2));
  int kmax = min(j1+j2-j3,min(j1-m1,j2+m2));
  double s=0.0;
  for(int k=kmin;k<=kmax;++k){
    double d = dfact(k)*dfact(j1+j2-j3-k)*dfact(j1-m1-k)*dfact(j2+m2-k)*dfact(j3-j2+m1+k)*dfact(j3-j1-m2+k);
    s += ((k&1)?-1.0:1.0)/d;
  }
  return pre*s;
}

__device__ __forceinline__ int gidx(int l,int l2,int combo,int lr,int kx,int l1,int m){
  return ((((((l*4+l2)*4+combo)*4+lr)*4+kx)*4+l1)*4+m);
}

__global__ void g_kernel(float* __restrict__ G){
  int tid = threadIdx.x;
  for(int e=tid;e<16384;e+=blockDim.x) G[e]=0.0f;
  __syncthreads();
  int trip = tid >> 4;
  int sub  = tid & 15;
  int lr = sub >> 2, m = sub & 3;
  int idx=0;
  for(int l=0;l<4;l++)for(int l1=0;l1<4;l1++){
    int lo=abs(l-l1), hi=min(3,l+l1);
    for(int l2=lo;l2<=hi;l2++){
      if(idx==trip && lr<=l && m<=l1){
        double c = 8.0*PI_D*PI_D/(2.0*l1+1.0)
                 * sqrt((2.0*l+1.0)*(2.0*l1+1.0)/(4.0*PI_D*(2.0*l2+1.0)))
                 * cg_coef(l,0,l1,0,l2,0);
        if(lr+m<=l2){
          float f = (float)(c * cg_coef(l,lr,l1,m,l2,lr+m) * ((m&1)?-1.0:1.0));
          G[gidx(l,l2,0,lr,lr+m,l1,m)] += f;
          G[gidx(l,l2,1,lr,lr+m,l1,m)] -= f;
          G[gidx(l,l2,2,lr,lr+m,l1,m)] += f;
          G[gidx(l,l2,3,lr,lr+m,l1,m)] += f;
        }
        if(m>0 && abs(lr-m)<=l2){
          if(lr-m>=0){
            float f = (float)(c * cg_coef(l,lr,l1,-m,l2,lr-m) * ((l1&1)?-1.0:1.0));
            G[gidx(l,l2,0,lr,lr-m,l1,m)] += f;
            G[gidx(l,l2,1,lr,lr-m,l1,m)] += f;
            G[gidx(l,l2,2,lr,lr-m,l1,m)] -= f;
            G[gidx(l,l2,3,lr,lr-m,l1,m)] += f;
          } else {
            float f = (float)(c * (((m-lr)&1)?-1.0:1.0) * (((l1+l2)&1)?-1.0:1.0)
                              * cg_coef(l,lr,l1,-m,l2,lr-m));
            G[gidx(l,l2,0,lr,m-lr,l1,m)] += f;
            G[gidx(l,l2,1,lr,m-lr,l1,m)] -= f;
            G[gidx(l,l2,2,lr,m-lr,l1,m)] -= f;
            G[gidx(l,l2,3,lr,m-lr,l1,m)] -= f;
          }
        }
      }
      idx++;
    }
  }
}

__device__ __forceinline__ void decode_kb(int kb,int& l2,int& partp,int& kx,int& t){
  int kbo;
  if(kb<30){l2=0;kbo=0;} else if(kb<90){l2=1;kbo=30;} else if(kb<180){l2=2;kbo=90;} else {l2=3;kbo=180;}
  int rem = kb-kbo;
  int per = (l2+1)*15;
  partp = rem/per;
  int q = rem%per;
  kx = q/15; t = q%15;
}

__device__ __forceinline__ void decode_col(int col,int& l,int& part,int& lr,int& j){
  int co;
  if(col<32){l=0;co=0;} else if(col<96){l=1;co=32;} else if(col<192){l=2;co=96;} else {l=3;co=192;}
  int cr = col-co; int per=(l+1)*16;
  part = cr/per; int q = cr%per; lr = q>>4; j = q&15;
}

// W'[p][col][K] bf16
__global__ void w_kernel(const float* __restrict__ G, Ptrs8 wp, ushort* __restrict__ W){
  long e = (long)blockIdx.x*256 + threadIdx.x;
  if(e >= 5L*320*4800) return;
  int K = (int)(e%4800); long r = e/4800; int col = (int)(r%320); int p = (int)(r/320);
  int i = K & 15; int kb = K >> 4;
  int l2,partp,kx,t; decode_kb(kb,l2,partp,kx,t);
  int l,part,lr,j; decode_col(col,l,part,lr,j);
  int combo = (part==0) ? (partp==0?0:1) : (partp==0?2:3);
  int wpart = (combo==0||combo==3)?0:1;
  int mstart = wpart?1:0;
  int woff = t*1280 + p*256 + i*16 + j;
  float acc=0.f;
  for(int l1=0;l1<4;l1++){
    const float* wptr = wp.p[l1*2+wpart];
    int gb = ((((l*4+l2)*4+combo)*4+lr)*4+kx)*16 + l1*4;
    for(int m=mstart;m<=l1;m++){
      float g = G[gb+m];
      if(g!=0.f) acc += g * wptr[m*19200 + woff];
    }
  }
  W[e] = f2bf(acc);
}

// ---------------- GEMM: out[8192x320] = X[8192x4800] * W'[4800x320], per p ----
// block 256 thr = 4 waves; tile 64 rows x 320 cols; wave w: cols w*80..+79
// A: 64x64 bf16 in LDS, double buffered, XOR-swizzled (T2). B: direct global b128.

__device__ __forceinline__ void a_load(const Ptrs8& xp, int p, int n0, int kt, int w, int lane, float4* v){
  int kb = kt*4 + w;
  int l2,partp,kx,t; decode_kb(kb,l2,partp,kx,t);
  const float* xb = xp.p[l2*2+partp];
  int nstr = 1200*(l2+1);
  const float* base = xb + (long)(n0 + (lane>>2))*nstr + (t*(l2+1)+kx)*80 + p*16 + (lane&3)*4;
  long step = (long)16*nstr;
  #pragma unroll
  for(int s=0;s<4;++s) v[s] = *(const float4*)(base + s*step);
}

__device__ __forceinline__ void a_store(ushort* As, int w, int lane, const float4* v){
  int rsub = lane>>2, c4 = (lane&3)*4;
  #pragma unroll
  for(int s=0;s<4;++s){
    int row = s*16 + rsub;
    int e = row*64 + ((w*16 + c4) ^ ((row&7)<<3));
    uint2 d;
    d.x = (uint)f2bf(v[s].x) | ((uint)f2bf(v[s].y)<<16);
    d.y = (uint)f2bf(v[s].z) | ((uint)f2bf(v[s].w)<<16);
    *(uint2*)(As + e) = d;
  }
}

__device__ __forceinline__ void b_load(const ushort* Wp, int w, int lane, int kt, short8* b){
  const ushort* q = Wp + (long)(w*80 + (lane&15))*4800 + kt*64 + ((lane>>4)*8);
  #pragma unroll
  for(int ks=0;ks<2;++ks)
    #pragma unroll
    for(int ni=0;ni<5;++ni)
      b[ks*5+ni] = *(const short8*)(q + (long)ni*16*4800 + ks*32);
}

__device__ __forceinline__ void do_mfma(const ushort* As, int lane, const short8* b, f32x4 acc[4][5]){
  #pragma unroll
  for(int ks=0;ks<2;++ks){
    short8 af[4];
    #pragma unroll
    for(int mi=0;mi<4;++mi){
      int row = mi*16 + (lane&15);
      int e = row*64 + (((ks*32) + (lane>>4)*8) ^ ((row&7)<<3));
      af[mi] = *(const short8*)(As + e);
    }
    #pragma unroll
    for(int mi=0;mi<4;++mi)
      #pragma unroll
      for(int ni=0;ni<5;++ni)
        acc[mi][ni] = __builtin_amdgcn_mfma_f32_16x16x32_bf16(af[mi], b[ks*5+ni], acc[mi][ni], 0,0,0);
  }
}

__global__ __launch_bounds__(256,2) void gemm_kernel(Ptrs8 xp, const ushort* __restrict__ Wb,
                                                     Ptrs8 bp, float* __restrict__ out){
  __shared__ ushort As[2][4096];
  const int tid = threadIdx.x;
  const int lane = tid & 63;
  const int w = tid >> 6;
  const int nb = blockIdx.x, p = blockIdx.y;
  const int n0 = nb*64;
  const ushort* Wp = Wb + (long)p*320*4800;

  f32x4 acc[4][5] = {};
  float4 av[4];
  short8 bfr[10];

  a_load(xp, p, n0, 0, w, lane, av);
  a_store(&As[0][0], w, lane, av);
  b_load(Wp, w, lane, 0, bfr);
  __syncthreads();

  int buf = 0;
  #pragma unroll 1
  for(int kt=0;kt<74;++kt){
    a_load(xp, p, n0, kt+1, w, lane, av);       // HBM prefetch (next tile)
    do_mfma(&As[buf][0], lane, bfr, acc);       // compute current
    b_load(Wp, w, lane, kt+1, bfr);             // L2-resident B for next
    a_store(&As[buf^1][0], w, lane, av);        // cvt + LDS write (next buffer)
    __syncthreads();
    buf ^= 1;
  }
  do_mfma(&As[buf][0], lane, bfr, acc);

  // epilogue
  int j = lane & 15, rg = (lane>>4)*4;
  #pragma unroll
  for(int ni=0;ni<5;++ni){
    int col16 = w*5 + ni;
    int l, part, lr;
    if(col16<2){l=0;part=col16;lr=0;}
    else if(col16<6){int c=col16-2;l=1;part=c>>1;lr=c&1;}
    else if(col16<12){int c=col16-6;l=2;part=(c>=3);lr=part?(c-3):c;}
    else {int c=col16-12;l=3;part=c>>2;lr=c&3;}
    float bv = 0.f;
    if(!(part==1 && lr==0)) bv = bp.p[l*2+part][lr*80 + p*16 + j];
    long base = 655360L*(l+1)*(l+part);
    int nst = (l+1)*80;
    long ioff = base + lr*80 + p*16 + j;
    #pragma unroll
    for(int mi=0;mi<4;++mi){
      int n = n0 + mi*16 + rg;
      #pragma unroll
      for(int r=0;r<4;++r)
        out[ioff + (long)(n+r)*nst] = acc[mi][ni][r] + bv;
    }
  }
}

extern "C" void kernel_launch(void* const* d_in, const int* in_sizes, int n_in,
                              void* d_out, int out_size, void* d_ws, size_t ws_size,
                              hipStream_t stream){
  Ptrs8 xp, wp, bp;
  for(int i=0;i<8;i++){
    xp.p[i] = (const float*)d_in[i];
    wp.p[i] = (const float*)d_in[8+i];
    bp.p[i] = (const float*)d_in[16+i];
  }
  float* G = (float*)d_ws;
  ushort* W = (ushort*)((char*)d_ws + 16384*4);
  g_kernel<<<dim3(1), dim3(576), 0, stream>>>(G);
  w_kernel<<<dim3(30000), dim3(256), 0, stream>>>(G, wp, W);
  gemm_kernel<<<dim3(128,5), dim3(256), 0, stream>>>(xp, W, bp, (float*)d_out);
}